// Round 6
// baseline (394.613 us; speedup 1.0000x reference)
//
#include <hip/hip_runtime.h>
#include <hip/hip_bf16.h>
#include <stdint.h>

// ---------------------------------------------------------------------------
// PairRepulsionSwitch: per-edge ZBL + r^-12 repulsion, quarter-summed to both
// endpoint nodes.
//
// R1/R2: global fp32 atomics memory-side rate-limited (~20G/s) -> 655/621us.
// R3: bucket binning -> 373us (write amp + low occupancy).
// R4: LDS counting sort -> 327us (51M LDS atomics + double edge read).
// R5: node-range multipass + LDS accumulators -> 273us; accum VALU-issue
//     bound: energy body runs under exec mask for ~every wave (24% lanes
//     active) -> 119M wave-instr.
// R6: per-wave stream compaction. Filter enqueues hit edges into a 128-entry
//     per-wave LDS ring (ballot+popcount positions); dense batches of 64 run
//     energy at full lane utilization. NR=8448 -> 39.9KB LDS -> 4 blocks/CU.
//     partial stored bf16 (halves combine traffic).
// ---------------------------------------------------------------------------

#define KE_CONST 14.3996454784255f
constexpr float INV_AC = 1.0f / (0.88534f * 0.52917721092f);

#define NR 8448              // nodes per range (33 KB accumulator)
#define QCAP 128             // per-wave ring capacity (must be 128: max pending 127)

// ---------------------------------------------------------------- shared math
__device__ __forceinline__ float edge_energy(float len, float2 zi, float2 zj,
                                             float inv_rmax) {
    float r = fmaxf(len, 0.2f);                 // R_MIN clamp
    float inv_r = 1.0f / r;

    // poly cutoff: (1 - clip(r/r_max,0,1))^6
    float u = fmaxf(1.0f - r * inv_rmax, 0.0f);
    float u2 = u * u;
    float pc = u2 * u2 * u2;

    // ZBL screened Coulomb
    float x = r * (zi.y + zj.y) * INV_AC;
    float phi = 0.1818f   * __expf(-3.2f    * x)
              + 0.5099f   * __expf(-0.9423f * x)
              + 0.2802f   * __expf(-0.4029f * x)
              + 0.02817f  * __expf(-0.2016f * x);
    float v_zbl = KE_CONST * zi.x * zj.x * phi * inv_r * pc;

    // C12 / r^12 with smoothstep switch at rc=1.5, width=0.2
    float ir2 = inv_r * inv_r;
    float ir4 = ir2 * ir2;
    float ir12 = ir4 * ir4 * ir4;
    float t = fminf(fmaxf((1.5f - r) * 5.0f, 0.0f), 1.0f);  // /width=0.2
    float sm = t * t * (3.0f - 2.0f * t);
    float v_r12 = 1e-4f * ir12 * pc * sm;

    return 0.25f * (v_zbl + v_r12);             // quarter to each endpoint
}

__device__ __forceinline__ uint16_t f32_to_bf16_rne(float v) {
    uint32_t u = __float_as_uint(v);
    u += 0x7FFFu + ((u >> 16) & 1u);
    return (uint16_t)(u >> 16);
}

__global__ void prep_nodes_kernel(const float* __restrict__ node_attrs,
                                  const float* __restrict__ atomic_numbers,
                                  float2* __restrict__ ztab,
                                  int n_nodes, int n_elem) {
    int i = blockIdx.x * blockDim.x + threadIdx.x;
    if (i >= n_nodes) return;
    float z = 0.0f;
    for (int k = 0; k < n_elem; ++k)
        z += node_attrs[i * n_elem + k] * atomic_numbers[k];
    ztab[i] = make_float2(z, powf(z, 0.23f));
}

// --------------------------------------------------------------- accumulate
__global__ __launch_bounds__(256) void accum_kernel(
    const float* __restrict__ lengths,
    const int* __restrict__ src, const int* __restrict__ dst,
    const float2* __restrict__ ztab,
    const float* __restrict__ rmax_ptr,
    uint16_t* __restrict__ partial,      // S rows of npad bf16
    int n_edges, int S, int EPB, int npad) {
    __shared__ float acc[NR];
    __shared__ int   qsi[4 * QCAP];
    __shared__ int   qdi[4 * QCAP];
    __shared__ float qln[4 * QCAP];

    int tid = threadIdx.x;
    int wv = tid >> 6, ln = tid & 63;
    for (int i = tid; i < NR; i += 256) acc[i] = 0.0f;
    __syncthreads();

    int s = blockIdx.x % S;
    int p = blockIdx.x / S;
    const unsigned base = (unsigned)p * NR;
    const float inv_rmax = 1.0f / rmax_ptr[0];

    int e0 = s * EPB;
    int e1 = min(e0 + EPB, n_edges);
    int WQ = EPB >> 2;                    // EPB is a multiple of 256
    int we0 = e0 + wv * WQ;
    int we1 = min(we0 + WQ, e1);

    int*   __restrict__ qs = qsi + wv * QCAP;
    int*   __restrict__ qd = qdi + wv * QCAP;
    float* __restrict__ ql = qln + wv * QCAP;

    unsigned wcnt = 0, wdone = 0;
    const unsigned long long lmask = (1ull << ln) - 1ull;

    for (int eb = we0; eb < we1; eb += 64) {
        int e = eb + ln;
        bool v = e < we1;
        int ec = v ? e : (n_edges - 1);
        int si = src[ec];
        int di = dst[ec];
        float len = lengths[ec];
        unsigned ls = (unsigned)si - base;
        unsigned ld = (unsigned)di - base;
        bool hit = v && ((ls < NR) || (ld < NR));
        unsigned long long m = __ballot(hit);
        if (hit) {
            unsigned slot = (wcnt + (unsigned)__popcll(m & lmask)) & (QCAP - 1);
            qs[slot] = si; qd[slot] = di; ql[slot] = len;
        }
        wcnt += (unsigned)__popcll(m);
        if (wcnt - wdone >= 64) {
            unsigned slot = (wdone + ln) & (QCAP - 1);
            int si2 = qs[slot];
            int di2 = qd[slot];
            float l2 = ql[slot];
            float2 zi = ztab[si2], zj = ztab[di2];
            float q = edge_energy(l2, zi, zj, inv_rmax);
            unsigned a = (unsigned)si2 - base;
            unsigned b = (unsigned)di2 - base;
            if (a < NR) atomicAdd(&acc[a], q);
            if (b < NR) atomicAdd(&acc[b], q);
            wdone += 64;
        }
    }
    // flush remainder (< 64 items)
    unsigned rem = wcnt - wdone;
    if (ln < rem) {
        unsigned slot = (wdone + ln) & (QCAP - 1);
        int si2 = qs[slot];
        int di2 = qd[slot];
        float l2 = ql[slot];
        float2 zi = ztab[si2], zj = ztab[di2];
        float q = edge_energy(l2, zi, zj, inv_rmax);
        unsigned a = (unsigned)si2 - base;
        unsigned b = (unsigned)di2 - base;
        if (a < NR) atomicAdd(&acc[a], q);
        if (b < NR) atomicAdd(&acc[b], q);
    }
    __syncthreads();

    uint16_t* __restrict__ row = partial + (size_t)s * npad + base;
    for (int i = tid; i < NR; i += 256)
        row[i] = f32_to_bf16_rne(acc[i]);
}

__global__ void combine_kernel(const uint16_t* __restrict__ partial,
                               float* __restrict__ out,
                               int n_nodes, int S, int npad) {
    int i = blockIdx.x * blockDim.x + threadIdx.x;
    if (i >= n_nodes) return;
    float t = 0.0f;
    for (int s = 0; s < S; ++s) {
        uint32_t h = partial[(size_t)s * npad + i];
        t += __uint_as_float(h << 16);
    }
    out[i] = t;
}

// ----------------------------------------------------------- fallback (R2)
__global__ void zero_out_kernel(float* __restrict__ out, int n) {
    int i = blockIdx.x * blockDim.x + threadIdx.x;
    if (i < n) out[i] = 0.0f;
}

__global__ __launch_bounds__(256) void edge_kernel_atomic(
    const float* __restrict__ lengths,
    const int* __restrict__ src_idx,
    const int* __restrict__ dst_idx,
    const float2* __restrict__ ztab,
    const float* __restrict__ rmax_ptr,
    float* __restrict__ out,
    int n_edges) {
    const float inv_rmax = 1.0f / rmax_ptr[0];
    int t = blockIdx.x * blockDim.x + threadIdx.x;
    int base = t * 4;
    if (base + 3 < n_edges) {
        float4 L = *reinterpret_cast<const float4*>(lengths + base);
        int4 S = *reinterpret_cast<const int4*>(src_idx + base);
        int4 D = *reinterpret_cast<const int4*>(dst_idx + base);
        float l[4] = {L.x, L.y, L.z, L.w};
        int s[4] = {S.x, S.y, S.z, S.w};
        int d[4] = {D.x, D.y, D.z, D.w};
        float2 zs[4], zd[4];
#pragma unroll
        for (int k = 0; k < 4; ++k) { zs[k] = ztab[s[k]]; zd[k] = ztab[d[k]]; }
#pragma unroll
        for (int k = 0; k < 4; ++k) {
            float q = edge_energy(l[k], zs[k], zd[k], inv_rmax);
            unsafeAtomicAdd(&out[s[k]], q);
            unsafeAtomicAdd(&out[d[k]], q);
        }
    } else if (base < n_edges) {
        for (int e = base; e < n_edges; ++e) {
            int si = src_idx[e], di = dst_idx[e];
            float q = edge_energy(lengths[e], ztab[si], ztab[di], inv_rmax);
            unsafeAtomicAdd(&out[si], q);
            unsafeAtomicAdd(&out[di], q);
        }
    }
}

// ---------------------------------------------------------------- launcher
extern "C" void kernel_launch(void* const* d_in, const int* in_sizes, int n_in,
                              void* d_out, int out_size, void* d_ws, size_t ws_size,
                              hipStream_t stream) {
    const float* lengths        = (const float*)d_in[0];
    const float* node_attrs     = (const float*)d_in[1];
    const int*   edge_index     = (const int*)d_in[2];
    const float* atomic_numbers = (const float*)d_in[3];
    const float* rmax_ptr       = (const float*)d_in[4];

    int n_edges = in_sizes[0];
    int n_elem  = in_sizes[3];
    int n_nodes = out_size;
    float* out = (float*)d_out;

    const int* src = edge_index;
    const int* dst = edge_index + n_edges;

    int P    = (n_nodes + NR - 1) / NR;
    int npad = P * NR;

    // Target grid ~1020 blocks (255 CUs x 4 resident); shrink S if ws tight.
    int S = (1020 + P - 1) / P;
    if (S < 1) S = 1;
    size_t zoff = 0, need = 0;
    for (; S >= 1; --S) {
        zoff = ((size_t)S * npad * sizeof(uint16_t) + 7) & ~(size_t)7;
        need = zoff + (size_t)n_nodes * sizeof(float2);
        if (need <= ws_size) break;
    }

    int nb_nodes = (n_nodes + 255) / 256;

    if (S >= 1) {
        uint16_t* partial = (uint16_t*)d_ws;
        float2*   ztab    = (float2*)((char*)d_ws + zoff);
        int EPB = (((n_edges + S - 1) / S) + 255) & ~255;  // mult of 256

        prep_nodes_kernel<<<nb_nodes, 256, 0, stream>>>(
            node_attrs, atomic_numbers, ztab, n_nodes, n_elem);
        accum_kernel<<<P * S, 256, 0, stream>>>(
            lengths, src, dst, ztab, rmax_ptr, partial,
            n_edges, S, EPB, npad);
        combine_kernel<<<nb_nodes, 256, 0, stream>>>(
            partial, out, n_nodes, S, npad);
    } else {
        // fallback: replicated-atomic path (R2)
        int stride = ((n_nodes + 49) / 2) * 2;
        int R = 16;
        while (R > 1 &&
               (size_t)R * stride * sizeof(float) + (size_t)n_nodes * sizeof(float2)
                   > ws_size)
            R >>= 1;
        float2* ztab = (float2*)((char*)d_ws + (size_t)R * stride * sizeof(float));
        hipMemsetAsync(d_ws, 0, (size_t)R * stride * sizeof(float), stream);
        prep_nodes_kernel<<<nb_nodes, 256, 0, stream>>>(
            node_attrs, atomic_numbers, ztab, n_nodes, n_elem);
        zero_out_kernel<<<nb_nodes, 256, 0, stream>>>(out, n_nodes);
        int n_thread4 = (n_edges + 3) / 4;
        int nb_edges = (n_thread4 + 255) / 256;
        edge_kernel_atomic<<<nb_edges, 256, 0, stream>>>(
            lengths, src, dst, ztab, rmax_ptr, out, n_edges);
    }
}

// Round 7
// 278.430 us; speedup vs baseline: 1.4173x; 1.4173x over previous
//
#include <hip/hip_runtime.h>
#include <hip/hip_bf16.h>
#include <stdint.h>

// ---------------------------------------------------------------------------
// PairRepulsionSwitch: per-edge ZBL + r^-12 repulsion, quarter-summed to both
// endpoint nodes.
//
// R1/R2: global fp32 atomics memory-side rate-limited (~20G/s) -> 655/621us.
// R3: bucket binning -> 373us. R4: LDS counting sort -> 327us.
// R5: node-range multipass + LDS accum -> 273us (VALU-divergence bound).
// R6: wave compaction halved per-visit VALU cost BUT S=85 broke the S%8==0
//     XCD swizzle -> each XCD re-fetched the edge stream (FETCH 42->330MB),
//     394us. Lesson: same-slice p-variants MUST share an XCD.
// R7: S forced to multiple of 8 (grid P*S <= 1024, all co-resident); filter
//     reads only src/dst as int4 (4 edges/lane), queue holds edge ids only;
//     dense batches gather src/dst/len/ztab from L2 and run energy at full
//     lane utilization; ds_add_f32 into 33KB LDS accumulator (4 blocks/CU).
// ---------------------------------------------------------------------------

#define KE_CONST 14.3996454784255f
constexpr float INV_AC = 1.0f / (0.88534f * 0.52917721092f);

#define NR 8448              // nodes per range (33 KB accumulator)
#define QCAP 128             // per-wave ring capacity (pending < 128 always)

// ---------------------------------------------------------------- shared math
__device__ __forceinline__ float edge_energy(float len, float2 zi, float2 zj,
                                             float inv_rmax) {
    float r = fmaxf(len, 0.2f);                 // R_MIN clamp
    float inv_r = 1.0f / r;

    // poly cutoff: (1 - clip(r/r_max,0,1))^6
    float u = fmaxf(1.0f - r * inv_rmax, 0.0f);
    float u2 = u * u;
    float pc = u2 * u2 * u2;

    // ZBL screened Coulomb
    float x = r * (zi.y + zj.y) * INV_AC;
    float phi = 0.1818f   * __expf(-3.2f    * x)
              + 0.5099f   * __expf(-0.9423f * x)
              + 0.2802f   * __expf(-0.4029f * x)
              + 0.02817f  * __expf(-0.2016f * x);
    float v_zbl = KE_CONST * zi.x * zj.x * phi * inv_r * pc;

    // C12 / r^12 with smoothstep switch at rc=1.5, width=0.2
    float ir2 = inv_r * inv_r;
    float ir4 = ir2 * ir2;
    float ir12 = ir4 * ir4 * ir4;
    float t = fminf(fmaxf((1.5f - r) * 5.0f, 0.0f), 1.0f);  // /width=0.2
    float sm = t * t * (3.0f - 2.0f * t);
    float v_r12 = 1e-4f * ir12 * pc * sm;

    return 0.25f * (v_zbl + v_r12);             // quarter to each endpoint
}

__device__ __forceinline__ uint16_t f32_to_bf16_rne(float v) {
    uint32_t u = __float_as_uint(v);
    u += 0x7FFFu + ((u >> 16) & 1u);
    return (uint16_t)(u >> 16);
}

__global__ void prep_nodes_kernel(const float* __restrict__ node_attrs,
                                  const float* __restrict__ atomic_numbers,
                                  float2* __restrict__ ztab,
                                  int n_nodes, int n_elem) {
    int i = blockIdx.x * blockDim.x + threadIdx.x;
    if (i >= n_nodes) return;
    float z = 0.0f;
    for (int k = 0; k < n_elem; ++k)
        z += node_attrs[i * n_elem + k] * atomic_numbers[k];
    ztab[i] = make_float2(z, powf(z, 0.23f));
}

// --------------------------------------------------------------- accumulate
__device__ __forceinline__ void run_batch(
    const int* __restrict__ q, unsigned wdone, int ln, unsigned count,
    const int* __restrict__ src, const int* __restrict__ dst,
    const float* __restrict__ lengths, const float2* __restrict__ ztab,
    float* __restrict__ acc, unsigned base, float inv_rmax) {
    if ((unsigned)ln < count) {
        unsigned slot = (wdone + (unsigned)ln) & (QCAP - 1);
        int e = q[slot];
        int si = src[e], di = dst[e];
        float2 zi = ztab[si], zj = ztab[di];
        float qv = edge_energy(lengths[e], zi, zj, inv_rmax);
        unsigned a = (unsigned)si - base;
        unsigned b = (unsigned)di - base;
        if (a < NR) atomicAdd(&acc[a], qv);
        if (b < NR) atomicAdd(&acc[b], qv);
    }
}

__global__ __launch_bounds__(256) void accum_kernel(
    const float* __restrict__ lengths,
    const int* __restrict__ src, const int* __restrict__ dst,
    const float2* __restrict__ ztab,
    const float* __restrict__ rmax_ptr,
    uint16_t* __restrict__ partial,      // S rows of npad bf16
    int n_edges, int S, int EPB, int npad, int vec_ok) {
    __shared__ float acc[NR];
    __shared__ int   qe[4 * QCAP];

    int tid = threadIdx.x;
    int wv = tid >> 6, ln = tid & 63;
    for (int i = tid; i < NR; i += 256) acc[i] = 0.0f;
    __syncthreads();

    int s = blockIdx.x % S;              // S%8==0: same-s blocks -> same XCD
    int p = blockIdx.x / S;
    const unsigned base = (unsigned)p * NR;
    const float inv_rmax = 1.0f / rmax_ptr[0];

    int e0 = s * EPB;
    int e1 = min(e0 + EPB, n_edges);
    int WQ = EPB >> 2;                   // EPB multiple of 1024 -> WQ mult 256
    int we0 = e0 + wv * WQ;
    int we1 = min(we0 + WQ, e1);

    int* __restrict__ q = qe + wv * QCAP;
    unsigned wcnt = 0, wdone = 0;
    const unsigned long long lmask = (1ull << ln) - 1ull;

    int eb = we0;
    if (vec_ok) {
        // 256 edges per wave-iteration: each lane owns 4 consecutive edges.
        for (; eb + 256 <= we1; eb += 256) {
            int e4 = eb + ln * 4;
            int4 Sv = *reinterpret_cast<const int4*>(src + e4);
            int4 Dv = *reinterpret_cast<const int4*>(dst + e4);
            int sv[4] = {Sv.x, Sv.y, Sv.z, Sv.w};
            int dv[4] = {Dv.x, Dv.y, Dv.z, Dv.w};
#pragma unroll
            for (int k = 0; k < 4; ++k) {
                bool hit = (((unsigned)sv[k] - base) < NR) ||
                           (((unsigned)dv[k] - base) < NR);
                unsigned long long m = __ballot(hit);
                if (hit) {
                    unsigned slot =
                        (wcnt + (unsigned)__popcll(m & lmask)) & (QCAP - 1);
                    q[slot] = e4 + k;
                }
                wcnt += (unsigned)__popcll(m);
                if (wcnt - wdone >= 64) {
                    __builtin_amdgcn_wave_barrier();
                    run_batch(q, wdone, ln, 64, src, dst, lengths, ztab,
                              acc, base, inv_rmax);
                    wdone += 64;
                }
            }
        }
    }
    // masked scalar remainder (and the whole range if !vec_ok)
    for (; eb < we1; eb += 64) {
        int e = eb + ln;
        bool v = e < we1;
        int ec = v ? e : 0;
        int si = src[ec], di = dst[ec];
        bool hit = v && ((((unsigned)si - base) < NR) ||
                         (((unsigned)di - base) < NR));
        unsigned long long m = __ballot(hit);
        if (hit) {
            unsigned slot = (wcnt + (unsigned)__popcll(m & lmask)) & (QCAP - 1);
            q[slot] = e;
        }
        wcnt += (unsigned)__popcll(m);
        if (wcnt - wdone >= 64) {
            __builtin_amdgcn_wave_barrier();
            run_batch(q, wdone, ln, 64, src, dst, lengths, ztab,
                      acc, base, inv_rmax);
            wdone += 64;
        }
    }
    // flush remainder (< 64 items)
    __builtin_amdgcn_wave_barrier();
    run_batch(q, wdone, ln, wcnt - wdone, src, dst, lengths, ztab,
              acc, base, inv_rmax);
    __syncthreads();

    uint16_t* __restrict__ row = partial + (size_t)s * npad + base;
    for (int i = tid; i < NR; i += 256)
        row[i] = f32_to_bf16_rne(acc[i]);
}

__global__ void combine_kernel(const uint16_t* __restrict__ partial,
                               float* __restrict__ out,
                               int n_nodes, int S, int npad) {
    int i = blockIdx.x * blockDim.x + threadIdx.x;
    if (i >= n_nodes) return;
    float t = 0.0f;
    for (int s = 0; s < S; ++s) {
        uint32_t h = partial[(size_t)s * npad + i];
        t += __uint_as_float(h << 16);
    }
    out[i] = t;
}

// ----------------------------------------------------------- fallback (R2)
__global__ void zero_out_kernel(float* __restrict__ out, int n) {
    int i = blockIdx.x * blockDim.x + threadIdx.x;
    if (i < n) out[i] = 0.0f;
}

__global__ __launch_bounds__(256) void edge_kernel_atomic(
    const float* __restrict__ lengths,
    const int* __restrict__ src_idx,
    const int* __restrict__ dst_idx,
    const float2* __restrict__ ztab,
    const float* __restrict__ rmax_ptr,
    float* __restrict__ out,
    int n_edges) {
    const float inv_rmax = 1.0f / rmax_ptr[0];
    int t = blockIdx.x * blockDim.x + threadIdx.x;
    int base = t * 4;
    if (base + 3 < n_edges) {
        float4 L = *reinterpret_cast<const float4*>(lengths + base);
        int4 S = *reinterpret_cast<const int4*>(src_idx + base);
        int4 D = *reinterpret_cast<const int4*>(dst_idx + base);
        float l[4] = {L.x, L.y, L.z, L.w};
        int s[4] = {S.x, S.y, S.z, S.w};
        int d[4] = {D.x, D.y, D.z, D.w};
        float2 zs[4], zd[4];
#pragma unroll
        for (int k = 0; k < 4; ++k) { zs[k] = ztab[s[k]]; zd[k] = ztab[d[k]]; }
#pragma unroll
        for (int k = 0; k < 4; ++k) {
            float q = edge_energy(l[k], zs[k], zd[k], inv_rmax);
            unsafeAtomicAdd(&out[s[k]], q);
            unsafeAtomicAdd(&out[d[k]], q);
        }
    } else if (base < n_edges) {
        for (int e = base; e < n_edges; ++e) {
            int si = src_idx[e], di = dst_idx[e];
            float q = edge_energy(lengths[e], ztab[si], ztab[di], inv_rmax);
            unsafeAtomicAdd(&out[si], q);
            unsafeAtomicAdd(&out[di], q);
        }
    }
}

// ---------------------------------------------------------------- launcher
extern "C" void kernel_launch(void* const* d_in, const int* in_sizes, int n_in,
                              void* d_out, int out_size, void* d_ws, size_t ws_size,
                              hipStream_t stream) {
    const float* lengths        = (const float*)d_in[0];
    const float* node_attrs     = (const float*)d_in[1];
    const int*   edge_index     = (const int*)d_in[2];
    const float* atomic_numbers = (const float*)d_in[3];
    const float* rmax_ptr       = (const float*)d_in[4];

    int n_edges = in_sizes[0];
    int n_elem  = in_sizes[3];
    int n_nodes = out_size;
    float* out = (float*)d_out;

    const int* src = edge_index;
    const int* dst = edge_index + n_edges;

    int P    = (n_nodes + NR - 1) / NR;
    int npad = P * NR;
    int vec_ok = ((n_edges & 3) == 0) ? 1 : 0;   // int4 alignment of dst

    // S: multiple of 8 (XCD co-location invariant!), grid P*S <= 1024 so all
    // blocks co-resident at 4/CU.
    int S = (1024 / P) & ~7;
    if (S < 8) S = 8;
    size_t zoff = 0, need = 0;
    for (; S >= 8; S -= 8) {
        zoff = ((size_t)S * npad * sizeof(uint16_t) + 7) & ~(size_t)7;
        need = zoff + (size_t)n_nodes * sizeof(float2);
        if (need <= ws_size) break;
    }

    int nb_nodes = (n_nodes + 255) / 256;

    if (S >= 8) {
        uint16_t* partial = (uint16_t*)d_ws;
        float2*   ztab    = (float2*)((char*)d_ws + zoff);
        int EPB = (((n_edges + S - 1) / S) + 1023) & ~1023;  // mult of 1024

        prep_nodes_kernel<<<nb_nodes, 256, 0, stream>>>(
            node_attrs, atomic_numbers, ztab, n_nodes, n_elem);
        accum_kernel<<<P * S, 256, 0, stream>>>(
            lengths, src, dst, ztab, rmax_ptr, partial,
            n_edges, S, EPB, npad, vec_ok);
        combine_kernel<<<nb_nodes, 256, 0, stream>>>(
            partial, out, n_nodes, S, npad);
    } else {
        // fallback: replicated-atomic path (R2)
        int stride = ((n_nodes + 49) / 2) * 2;
        int R = 16;
        while (R > 1 &&
               (size_t)R * stride * sizeof(float) + (size_t)n_nodes * sizeof(float2)
                   > ws_size)
            R >>= 1;
        float2* ztab = (float2*)((char*)d_ws + (size_t)R * stride * sizeof(float));
        hipMemsetAsync(d_ws, 0, (size_t)R * stride * sizeof(float), stream);
        prep_nodes_kernel<<<nb_nodes, 256, 0, stream>>>(
            node_attrs, atomic_numbers, ztab, n_nodes, n_elem);
        zero_out_kernel<<<nb_nodes, 256, 0, stream>>>(out, n_nodes);
        int n_thread4 = (n_edges + 3) / 4;
        int nb_edges = (n_thread4 + 255) / 256;
        edge_kernel_atomic<<<nb_edges, 256, 0, stream>>>(
            lengths, src, dst, ztab, rmax_ptr, out, n_edges);
    }
}

// Round 8
// 255.005 us; speedup vs baseline: 1.5475x; 1.0919x over previous
//
#include <hip/hip_runtime.h>
#include <hip/hip_bf16.h>
#include <stdint.h>

// ---------------------------------------------------------------------------
// PairRepulsionSwitch: per-edge ZBL + r^-12 repulsion, quarter-summed to both
// endpoint nodes.
//
// R1/R2: global fp32 atomics memory-side rate-limited (~20G/s) -> 655/621us.
// R3: bucket binning -> 373us. R4: LDS counting sort -> 327us.
// R5: node-range multipass + LDS accum -> 273us (divergence-bound).
// R6: wave compaction works, but S=85 broke S%8==0 XCD swizzle -> FETCH
//     42->330MB, 394us. Same-slice p-variants MUST share an XCD.
// R7: S%8 fixed (FETCH back to 41MB) but id-only queue created a dependent
//     gather chain (q->src/dst/len->ztab) and LDS capped occupancy at 13
//     waves/CU -> latency-bound at 180us (VALU 31%, HBM 4%).
// R8: queue stores {si,di,len} (one gather level: ztab only) + 512-thread
//     blocks (45KB LDS -> 3 blocks/CU x 8 waves = 24 waves/CU). Grid
//     P*S = 12*64 = 768 = 3/CU exactly, S%8==0 keeps XCD locality.
// ---------------------------------------------------------------------------

#define KE_CONST 14.3996454784255f
constexpr float INV_AC = 1.0f / (0.88534f * 0.52917721092f);

#define NR 8448              // nodes per range (33 KB accumulator)
#define QCAP 128             // per-wave ring capacity (pending <= 127 always)
#define NW 8                 // waves per block (512 threads)

// ---------------------------------------------------------------- shared math
__device__ __forceinline__ float edge_energy(float len, float2 zi, float2 zj,
                                             float inv_rmax) {
    float r = fmaxf(len, 0.2f);                 // R_MIN clamp
    float inv_r = 1.0f / r;

    // poly cutoff: (1 - clip(r/r_max,0,1))^6
    float u = fmaxf(1.0f - r * inv_rmax, 0.0f);
    float u2 = u * u;
    float pc = u2 * u2 * u2;

    // ZBL screened Coulomb
    float x = r * (zi.y + zj.y) * INV_AC;
    float phi = 0.1818f   * __expf(-3.2f    * x)
              + 0.5099f   * __expf(-0.9423f * x)
              + 0.2802f   * __expf(-0.4029f * x)
              + 0.02817f  * __expf(-0.2016f * x);
    float v_zbl = KE_CONST * zi.x * zj.x * phi * inv_r * pc;

    // C12 / r^12 with smoothstep switch at rc=1.5, width=0.2
    float ir2 = inv_r * inv_r;
    float ir4 = ir2 * ir2;
    float ir12 = ir4 * ir4 * ir4;
    float t = fminf(fmaxf((1.5f - r) * 5.0f, 0.0f), 1.0f);  // /width=0.2
    float sm = t * t * (3.0f - 2.0f * t);
    float v_r12 = 1e-4f * ir12 * pc * sm;

    return 0.25f * (v_zbl + v_r12);             // quarter to each endpoint
}

__device__ __forceinline__ uint16_t f32_to_bf16_rne(float v) {
    uint32_t u = __float_as_uint(v);
    u += 0x7FFFu + ((u >> 16) & 1u);
    return (uint16_t)(u >> 16);
}

__global__ void prep_nodes_kernel(const float* __restrict__ node_attrs,
                                  const float* __restrict__ atomic_numbers,
                                  float2* __restrict__ ztab,
                                  int n_nodes, int n_elem) {
    int i = blockIdx.x * blockDim.x + threadIdx.x;
    if (i >= n_nodes) return;
    float z = 0.0f;
    for (int k = 0; k < n_elem; ++k)
        z += node_attrs[i * n_elem + k] * atomic_numbers[k];
    ztab[i] = make_float2(z, powf(z, 0.23f));
}

// --------------------------------------------------------------- accumulate
__device__ __forceinline__ void run_batch(
    const int* __restrict__ qs, const int* __restrict__ qd,
    const float* __restrict__ ql, unsigned wdone, int ln, unsigned count,
    const float2* __restrict__ ztab,
    float* __restrict__ acc, unsigned base, float inv_rmax) {
    if ((unsigned)ln < count) {
        unsigned slot = (wdone + (unsigned)ln) & (QCAP - 1);
        int si = qs[slot];
        int di = qd[slot];
        float len = ql[slot];
        float2 zi = ztab[si], zj = ztab[di];
        float qv = edge_energy(len, zi, zj, inv_rmax);
        unsigned a = (unsigned)si - base;
        unsigned b = (unsigned)di - base;
        if (a < NR) atomicAdd(&acc[a], qv);
        if (b < NR) atomicAdd(&acc[b], qv);
    }
}

__global__ __launch_bounds__(512) void accum_kernel(
    const float* __restrict__ lengths,
    const int* __restrict__ src, const int* __restrict__ dst,
    const float2* __restrict__ ztab,
    const float* __restrict__ rmax_ptr,
    uint16_t* __restrict__ partial,      // S rows of npad bf16
    int n_edges, int S, int EPB, int npad, int vec_ok) {
    __shared__ float acc[NR];
    __shared__ int   qsi[NW * QCAP];
    __shared__ int   qdi[NW * QCAP];
    __shared__ float qln[NW * QCAP];

    int tid = threadIdx.x;
    int wv = tid >> 6, ln = tid & 63;
    for (int i = tid; i < NR; i += 512) acc[i] = 0.0f;
    __syncthreads();

    int s = blockIdx.x % S;              // S%8==0: same-s blocks -> same XCD
    int p = blockIdx.x / S;
    const unsigned base = (unsigned)p * NR;
    const float inv_rmax = 1.0f / rmax_ptr[0];

    int e0 = s * EPB;
    int e1 = min(e0 + EPB, n_edges);
    int WQ = EPB / NW;                   // EPB multiple of 2048 -> WQ mult 256
    int we0 = e0 + wv * WQ;
    int we1 = min(we0 + WQ, e1);

    int*   __restrict__ qs = qsi + wv * QCAP;
    int*   __restrict__ qd = qdi + wv * QCAP;
    float* __restrict__ ql = qln + wv * QCAP;
    unsigned wcnt = 0, wdone = 0;
    const unsigned long long lmask = (1ull << ln) - 1ull;

    int eb = we0;
    if (vec_ok) {
        // 256 edges per wave-iteration: each lane owns 4 consecutive edges.
        for (; eb + 256 <= we1; eb += 256) {
            int e4 = eb + ln * 4;
            int4   Sv = *reinterpret_cast<const int4*>(src + e4);
            int4   Dv = *reinterpret_cast<const int4*>(dst + e4);
            float4 Lv = *reinterpret_cast<const float4*>(lengths + e4);
            int   sv[4] = {Sv.x, Sv.y, Sv.z, Sv.w};
            int   dv[4] = {Dv.x, Dv.y, Dv.z, Dv.w};
            float lv[4] = {Lv.x, Lv.y, Lv.z, Lv.w};
#pragma unroll
            for (int k = 0; k < 4; ++k) {
                bool hit = (((unsigned)sv[k] - base) < NR) ||
                           (((unsigned)dv[k] - base) < NR);
                unsigned long long m = __ballot(hit);
                if (hit) {
                    unsigned slot =
                        (wcnt + (unsigned)__popcll(m & lmask)) & (QCAP - 1);
                    qs[slot] = sv[k]; qd[slot] = dv[k]; ql[slot] = lv[k];
                }
                wcnt += (unsigned)__popcll(m);
                if (wcnt - wdone >= 64) {
                    __builtin_amdgcn_wave_barrier();
                    run_batch(qs, qd, ql, wdone, ln, 64, ztab,
                              acc, base, inv_rmax);
                    wdone += 64;
                }
            }
        }
    }
    // masked scalar remainder (and the whole range if !vec_ok)
    for (; eb < we1; eb += 64) {
        int e = eb + ln;
        bool v = e < we1;
        int ec = v ? e : 0;
        int si = src[ec], di = dst[ec];
        float len = lengths[ec];
        bool hit = v && ((((unsigned)si - base) < NR) ||
                         (((unsigned)di - base) < NR));
        unsigned long long m = __ballot(hit);
        if (hit) {
            unsigned slot = (wcnt + (unsigned)__popcll(m & lmask)) & (QCAP - 1);
            qs[slot] = si; qd[slot] = di; ql[slot] = len;
        }
        wcnt += (unsigned)__popcll(m);
        if (wcnt - wdone >= 64) {
            __builtin_amdgcn_wave_barrier();
            run_batch(qs, qd, ql, wdone, ln, 64, ztab, acc, base, inv_rmax);
            wdone += 64;
        }
    }
    // flush remainder (< 64 items)
    __builtin_amdgcn_wave_barrier();
    run_batch(qs, qd, ql, wdone, ln, wcnt - wdone, ztab, acc, base, inv_rmax);
    __syncthreads();

    uint16_t* __restrict__ row = partial + (size_t)s * npad + base;
    for (int i = tid; i < NR; i += 512)
        row[i] = f32_to_bf16_rne(acc[i]);
}

__global__ void combine_kernel(const uint16_t* __restrict__ partial,
                               float* __restrict__ out,
                               int n_nodes, int S, int npad) {
    int i = blockIdx.x * blockDim.x + threadIdx.x;
    if (i >= n_nodes) return;
    float t = 0.0f;
    for (int s = 0; s < S; ++s) {
        uint32_t h = partial[(size_t)s * npad + i];
        t += __uint_as_float(h << 16);
    }
    out[i] = t;
}

// ----------------------------------------------------------- fallback (R2)
__global__ void zero_out_kernel(float* __restrict__ out, int n) {
    int i = blockIdx.x * blockDim.x + threadIdx.x;
    if (i < n) out[i] = 0.0f;
}

__global__ __launch_bounds__(256) void edge_kernel_atomic(
    const float* __restrict__ lengths,
    const int* __restrict__ src_idx,
    const int* __restrict__ dst_idx,
    const float2* __restrict__ ztab,
    const float* __restrict__ rmax_ptr,
    float* __restrict__ out,
    int n_edges) {
    const float inv_rmax = 1.0f / rmax_ptr[0];
    int t = blockIdx.x * blockDim.x + threadIdx.x;
    int base = t * 4;
    if (base + 3 < n_edges) {
        float4 L = *reinterpret_cast<const float4*>(lengths + base);
        int4 S = *reinterpret_cast<const int4*>(src_idx + base);
        int4 D = *reinterpret_cast<const int4*>(dst_idx + base);
        float l[4] = {L.x, L.y, L.z, L.w};
        int s[4] = {S.x, S.y, S.z, S.w};
        int d[4] = {D.x, D.y, D.z, D.w};
        float2 zs[4], zd[4];
#pragma unroll
        for (int k = 0; k < 4; ++k) { zs[k] = ztab[s[k]]; zd[k] = ztab[d[k]]; }
#pragma unroll
        for (int k = 0; k < 4; ++k) {
            float q = edge_energy(l[k], zs[k], zd[k], inv_rmax);
            unsafeAtomicAdd(&out[s[k]], q);
            unsafeAtomicAdd(&out[d[k]], q);
        }
    } else if (base < n_edges) {
        for (int e = base; e < n_edges; ++e) {
            int si = src_idx[e], di = dst_idx[e];
            float q = edge_energy(lengths[e], ztab[si], ztab[di], inv_rmax);
            unsafeAtomicAdd(&out[si], q);
            unsafeAtomicAdd(&out[di], q);
        }
    }
}

// ---------------------------------------------------------------- launcher
extern "C" void kernel_launch(void* const* d_in, const int* in_sizes, int n_in,
                              void* d_out, int out_size, void* d_ws, size_t ws_size,
                              hipStream_t stream) {
    const float* lengths        = (const float*)d_in[0];
    const float* node_attrs     = (const float*)d_in[1];
    const int*   edge_index     = (const int*)d_in[2];
    const float* atomic_numbers = (const float*)d_in[3];
    const float* rmax_ptr       = (const float*)d_in[4];

    int n_edges = in_sizes[0];
    int n_elem  = in_sizes[3];
    int n_nodes = out_size;
    float* out = (float*)d_out;

    const int* src = edge_index;
    const int* dst = edge_index + n_edges;

    int P    = (n_nodes + NR - 1) / NR;
    int npad = P * NR;
    int vec_ok = ((n_edges & 3) == 0) ? 1 : 0;   // int4 alignment of dst

    // S: multiple of 8 (XCD co-location invariant!), grid P*S ~= 768 so all
    // 512-thread blocks co-resident at 3/CU (45KB LDS each).
    int S = (768 / P) & ~7;
    if (S < 8) S = 8;
    size_t zoff = 0, need = 0;
    for (; S >= 8; S -= 8) {
        zoff = ((size_t)S * npad * sizeof(uint16_t) + 7) & ~(size_t)7;
        need = zoff + (size_t)n_nodes * sizeof(float2);
        if (need <= ws_size) break;
    }

    int nb_nodes = (n_nodes + 255) / 256;

    if (S >= 8) {
        uint16_t* partial = (uint16_t*)d_ws;
        float2*   ztab    = (float2*)((char*)d_ws + zoff);
        int EPB = (((n_edges + S - 1) / S) + 2047) & ~2047;  // mult of 2048

        prep_nodes_kernel<<<nb_nodes, 256, 0, stream>>>(
            node_attrs, atomic_numbers, ztab, n_nodes, n_elem);
        accum_kernel<<<P * S, 512, 0, stream>>>(
            lengths, src, dst, ztab, rmax_ptr, partial,
            n_edges, S, EPB, npad, vec_ok);
        combine_kernel<<<nb_nodes, 256, 0, stream>>>(
            partial, out, n_nodes, S, npad);
    } else {
        // fallback: replicated-atomic path (R2)
        int stride = ((n_nodes + 49) / 2) * 2;
        int R = 16;
        while (R > 1 &&
               (size_t)R * stride * sizeof(float) + (size_t)n_nodes * sizeof(float2)
                   > ws_size)
            R >>= 1;
        float2* ztab = (float2*)((char*)d_ws + (size_t)R * stride * sizeof(float));
        hipMemsetAsync(d_ws, 0, (size_t)R * stride * sizeof(float), stream);
        prep_nodes_kernel<<<nb_nodes, 256, 0, stream>>>(
            node_attrs, atomic_numbers, ztab, n_nodes, n_elem);
        zero_out_kernel<<<nb_nodes, 256, 0, stream>>>(out, n_nodes);
        int n_thread4 = (n_edges + 3) / 4;
        int nb_edges = (n_thread4 + 255) / 256;
        edge_kernel_atomic<<<nb_edges, 256, 0, stream>>>(
            lengths, src, dst, ztab, rmax_ptr, out, n_edges);
    }
}

// Round 9
// 252.738 us; speedup vs baseline: 1.5613x; 1.0090x over previous
//
#include <hip/hip_runtime.h>
#include <hip/hip_bf16.h>
#include <stdint.h>

// ---------------------------------------------------------------------------
// PairRepulsionSwitch: per-edge ZBL + r^-12 repulsion, quarter-summed to both
// endpoint nodes.
//
// R1/R2: global fp32 atomics memory-side rate-limited (~20G/s) -> 655/621us.
// R3: bucket binning -> 373us. R4: LDS counting sort -> 327us.
// R5: node-range multipass + LDS accum -> 273us (divergence-bound).
// R6: wave compaction; S%8 swizzle broken -> 394us (FETCH 330MB). Lesson:
//     same-slice p-variants MUST share an XCD (S multiple of 8).
// R7/R8: compaction tuned -> 255us; still ~60% stalled: drain chain
//     (queue->ztab gather->energy->LDS atomic) welded into filter loop,
//     76.8M redundant filter visits pay ballot/queue machinery.
// R9: split pipeline. (1) energy_kernel: dense per-edge energy, 100% lane
//     util, coalesced; q -> workspace fp32. (2) accum_kernel: P=8 passes,
//     only range-check + masked ds_add_f32 (no ballot/queue/energy/gather);
//     S=96 (mult of 8) keeps re-reads XCD-local; NR=12800, 512thr, 3
//     blocks/CU = 24 waves/CU. (3) combine bf16 partials.
// ---------------------------------------------------------------------------

#define KE_CONST 14.3996454784255f
constexpr float INV_AC = 1.0f / (0.88534f * 0.52917721092f);

#define NR 12800             // nodes per range (50 KB accumulator)

// ---------------------------------------------------------------- shared math
__device__ __forceinline__ float edge_energy(float len, float2 zi, float2 zj,
                                             float inv_rmax) {
    float r = fmaxf(len, 0.2f);                 // R_MIN clamp
    float inv_r = 1.0f / r;

    // poly cutoff: (1 - clip(r/r_max,0,1))^6
    float u = fmaxf(1.0f - r * inv_rmax, 0.0f);
    float u2 = u * u;
    float pc = u2 * u2 * u2;

    // ZBL screened Coulomb
    float x = r * (zi.y + zj.y) * INV_AC;
    float phi = 0.1818f   * __expf(-3.2f    * x)
              + 0.5099f   * __expf(-0.9423f * x)
              + 0.2802f   * __expf(-0.4029f * x)
              + 0.02817f  * __expf(-0.2016f * x);
    float v_zbl = KE_CONST * zi.x * zj.x * phi * inv_r * pc;

    // C12 / r^12 with smoothstep switch at rc=1.5, width=0.2
    float ir2 = inv_r * inv_r;
    float ir4 = ir2 * ir2;
    float ir12 = ir4 * ir4 * ir4;
    float t = fminf(fmaxf((1.5f - r) * 5.0f, 0.0f), 1.0f);  // /width=0.2
    float sm = t * t * (3.0f - 2.0f * t);
    float v_r12 = 1e-4f * ir12 * pc * sm;

    return 0.25f * (v_zbl + v_r12);             // quarter to each endpoint
}

__device__ __forceinline__ uint16_t f32_to_bf16_rne(float v) {
    uint32_t u = __float_as_uint(v);
    u += 0x7FFFu + ((u >> 16) & 1u);
    return (uint16_t)(u >> 16);
}

__global__ void prep_nodes_kernel(const float* __restrict__ node_attrs,
                                  const float* __restrict__ atomic_numbers,
                                  float2* __restrict__ ztab,
                                  int n_nodes, int n_elem) {
    int i = blockIdx.x * blockDim.x + threadIdx.x;
    if (i >= n_nodes) return;
    float z = 0.0f;
    for (int k = 0; k < n_elem; ++k)
        z += node_attrs[i * n_elem + k] * atomic_numbers[k];
    ztab[i] = make_float2(z, powf(z, 0.23f));
}

// ----------------------------------------------------- dense per-edge energy
__global__ __launch_bounds__(256) void energy_kernel(
    const float* __restrict__ lengths,
    const int* __restrict__ src, const int* __restrict__ dst,
    const float2* __restrict__ ztab,
    const float* __restrict__ rmax_ptr,
    float* __restrict__ qarr, int n_edges, int vec_ok) {
    const float inv_rmax = 1.0f / rmax_ptr[0];
    int t = blockIdx.x * blockDim.x + threadIdx.x;
    if (vec_ok) {
        int base = t * 4;
        if (base + 3 < n_edges) {
            float4 L  = *reinterpret_cast<const float4*>(lengths + base);
            int4   S4 = *reinterpret_cast<const int4*>(src + base);
            int4   D4 = *reinterpret_cast<const int4*>(dst + base);
            float2 zs0 = ztab[S4.x], zd0 = ztab[D4.x];
            float2 zs1 = ztab[S4.y], zd1 = ztab[D4.y];
            float2 zs2 = ztab[S4.z], zd2 = ztab[D4.z];
            float2 zs3 = ztab[S4.w], zd3 = ztab[D4.w];
            float4 Q;
            Q.x = edge_energy(L.x, zs0, zd0, inv_rmax);
            Q.y = edge_energy(L.y, zs1, zd1, inv_rmax);
            Q.z = edge_energy(L.z, zs2, zd2, inv_rmax);
            Q.w = edge_energy(L.w, zs3, zd3, inv_rmax);
            *reinterpret_cast<float4*>(qarr + base) = Q;
        } else {
            for (int e = base; e < n_edges; ++e)
                qarr[e] = edge_energy(lengths[e], ztab[src[e]], ztab[dst[e]],
                                      inv_rmax);
        }
    } else {
        int stride = gridDim.x * blockDim.x;
        for (int e = t; e < n_edges; e += stride)
            qarr[e] = edge_energy(lengths[e], ztab[src[e]], ztab[dst[e]],
                                  inv_rmax);
    }
}

// --------------------------------------------------------------- accumulate
__global__ __launch_bounds__(512) void accum_kernel(
    const int* __restrict__ src, const int* __restrict__ dst,
    const float* __restrict__ qarr,
    uint16_t* __restrict__ partial,      // S rows of npad bf16
    int n_edges, int S, int EPB, int npad, int vec_ok) {
    __shared__ float acc[NR];
    int tid = threadIdx.x;
    for (int i = tid; i < NR; i += 512) acc[i] = 0.0f;
    __syncthreads();

    int s = blockIdx.x % S;              // S%8==0: same-s blocks -> same XCD
    int p = blockIdx.x / S;
    const unsigned base = (unsigned)p * NR;

    int e0 = s * EPB;
    int e1 = min(e0 + EPB, n_edges);

    if (e0 < e1) {
        if (vec_ok) {
            // e0 mult of 2048, e1-e0 mult of 4 (n_edges%4==0): full quads.
            for (int off = e0 + tid * 4; off < e1; off += 512 * 4) {
                int4   S4 = *reinterpret_cast<const int4*>(src + off);
                int4   D4 = *reinterpret_cast<const int4*>(dst + off);
                float4 Q4 = *reinterpret_cast<const float4*>(qarr + off);
                int   sv[4] = {S4.x, S4.y, S4.z, S4.w};
                int   dv[4] = {D4.x, D4.y, D4.z, D4.w};
                float qv[4] = {Q4.x, Q4.y, Q4.z, Q4.w};
#pragma unroll
                for (int k = 0; k < 4; ++k) {
                    unsigned a = (unsigned)sv[k] - base;
                    if (a < NR) atomicAdd(&acc[a], qv[k]);
                    unsigned b = (unsigned)dv[k] - base;
                    if (b < NR) atomicAdd(&acc[b], qv[k]);
                }
            }
        } else {
            for (int e = e0 + tid; e < e1; e += 512) {
                unsigned a = (unsigned)src[e] - base;
                float q = qarr[e];
                if (a < NR) atomicAdd(&acc[a], q);
                unsigned b = (unsigned)dst[e] - base;
                if (b < NR) atomicAdd(&acc[b], q);
            }
        }
    }
    __syncthreads();

    uint16_t* __restrict__ row = partial + (size_t)s * npad + base;
    for (int i = tid; i < NR; i += 512)
        row[i] = f32_to_bf16_rne(acc[i]);
}

__global__ void combine_kernel(const uint16_t* __restrict__ partial,
                               float* __restrict__ out,
                               int n_nodes, int S, int npad) {
    int i = blockIdx.x * blockDim.x + threadIdx.x;
    if (i >= n_nodes) return;
    float t = 0.0f;
    for (int s = 0; s < S; ++s) {
        uint32_t h = partial[(size_t)s * npad + i];
        t += __uint_as_float(h << 16);
    }
    out[i] = t;
}

// ----------------------------------------------------------- fallback (R2)
__global__ void zero_out_kernel(float* __restrict__ out, int n) {
    int i = blockIdx.x * blockDim.x + threadIdx.x;
    if (i < n) out[i] = 0.0f;
}

__global__ __launch_bounds__(256) void edge_kernel_atomic(
    const float* __restrict__ lengths,
    const int* __restrict__ src_idx,
    const int* __restrict__ dst_idx,
    const float2* __restrict__ ztab,
    const float* __restrict__ rmax_ptr,
    float* __restrict__ out,
    int n_edges) {
    const float inv_rmax = 1.0f / rmax_ptr[0];
    int t = blockIdx.x * blockDim.x + threadIdx.x;
    int base = t * 4;
    if (base + 3 < n_edges) {
        float4 L = *reinterpret_cast<const float4*>(lengths + base);
        int4 S = *reinterpret_cast<const int4*>(src_idx + base);
        int4 D = *reinterpret_cast<const int4*>(dst_idx + base);
        float l[4] = {L.x, L.y, L.z, L.w};
        int s[4] = {S.x, S.y, S.z, S.w};
        int d[4] = {D.x, D.y, D.z, D.w};
        float2 zs[4], zd[4];
#pragma unroll
        for (int k = 0; k < 4; ++k) { zs[k] = ztab[s[k]]; zd[k] = ztab[d[k]]; }
#pragma unroll
        for (int k = 0; k < 4; ++k) {
            float q = edge_energy(l[k], zs[k], zd[k], inv_rmax);
            unsafeAtomicAdd(&out[s[k]], q);
            unsafeAtomicAdd(&out[d[k]], q);
        }
    } else if (base < n_edges) {
        for (int e = base; e < n_edges; ++e) {
            int si = src_idx[e], di = dst_idx[e];
            float q = edge_energy(lengths[e], ztab[si], ztab[di], inv_rmax);
            unsafeAtomicAdd(&out[si], q);
            unsafeAtomicAdd(&out[di], q);
        }
    }
}

// ---------------------------------------------------------------- launcher
extern "C" void kernel_launch(void* const* d_in, const int* in_sizes, int n_in,
                              void* d_out, int out_size, void* d_ws, size_t ws_size,
                              hipStream_t stream) {
    const float* lengths        = (const float*)d_in[0];
    const float* node_attrs     = (const float*)d_in[1];
    const int*   edge_index     = (const int*)d_in[2];
    const float* atomic_numbers = (const float*)d_in[3];
    const float* rmax_ptr       = (const float*)d_in[4];

    int n_edges = in_sizes[0];
    int n_elem  = in_sizes[3];
    int n_nodes = out_size;
    float* out = (float*)d_out;

    const int* src = edge_index;
    const int* dst = edge_index + n_edges;

    int P    = (n_nodes + NR - 1) / NR;
    int npad = P * NR;
    int vec_ok = ((n_edges & 3) == 0) ? 1 : 0;   // int4 alignment of dst

    // S: multiple of 8 (XCD co-location invariant), grid P*S <= 768 so all
    // 512-thread 50KB-LDS blocks are co-resident at 3/CU.
    int S = (768 / P) & ~7;
    if (S < 8) S = 8;

    // ws layout: qarr(n_edges f32) | partial(S*npad bf16) | ztab(float2)
    size_t q_bytes = ((size_t)n_edges * sizeof(float) + 255) & ~(size_t)255;
    size_t zoff = 0, need = 0;
    for (; S >= 8; S -= 8) {
        size_t part_bytes =
            ((size_t)S * npad * sizeof(uint16_t) + 255) & ~(size_t)255;
        zoff = q_bytes + part_bytes;
        need = zoff + (size_t)n_nodes * sizeof(float2);
        if (need <= ws_size) break;
    }

    int nb_nodes = (n_nodes + 255) / 256;

    if (S >= 8) {
        float*    qarr    = (float*)d_ws;
        uint16_t* partial = (uint16_t*)((char*)d_ws + q_bytes);
        float2*   ztab    = (float2*)((char*)d_ws + zoff);
        int EPB = (((n_edges + S - 1) / S) + 2047) & ~2047;  // mult of 2048

        prep_nodes_kernel<<<nb_nodes, 256, 0, stream>>>(
            node_attrs, atomic_numbers, ztab, n_nodes, n_elem);
        int nb_energy = ((n_edges + 3) / 4 + 255) / 256;
        energy_kernel<<<nb_energy, 256, 0, stream>>>(
            lengths, src, dst, ztab, rmax_ptr, qarr, n_edges, vec_ok);
        accum_kernel<<<P * S, 512, 0, stream>>>(
            src, dst, qarr, partial, n_edges, S, EPB, npad, vec_ok);
        combine_kernel<<<nb_nodes, 256, 0, stream>>>(
            partial, out, n_nodes, S, npad);
    } else {
        // fallback: replicated-atomic path (R2)
        int stride = ((n_nodes + 49) / 2) * 2;
        int R = 16;
        while (R > 1 &&
               (size_t)R * stride * sizeof(float) + (size_t)n_nodes * sizeof(float2)
                   > ws_size)
            R >>= 1;
        float2* ztab = (float2*)((char*)d_ws + (size_t)R * stride * sizeof(float));
        hipMemsetAsync(d_ws, 0, (size_t)R * stride * sizeof(float), stream);
        prep_nodes_kernel<<<nb_nodes, 256, 0, stream>>>(
            node_attrs, atomic_numbers, ztab, n_nodes, n_elem);
        zero_out_kernel<<<nb_nodes, 256, 0, stream>>>(out, n_nodes);
        int n_thread4 = (n_edges + 3) / 4;
        int nb_edges = (n_thread4 + 255) / 256;
        edge_kernel_atomic<<<nb_edges, 256, 0, stream>>>(
            lengths, src, dst, ztab, rmax_ptr, out, n_edges);
    }
}